// Round 1
// baseline (162.869 us; speedup 1.0000x reference)
//
#include <hip/hip_runtime.h>

// FourierKANLayer: y[n,o] = sum_{i,g} cos(x[n,i]*(g+1))*C[0,o,i,g]
//                         + sin(x[n,i]*(g+1))*C[1,o,i,g] + bias[o]
// N=8192 rows, I=512, O=512, G=8  ->  GEMM  [N x K] * [K x O], K = I*16 = 8192
// Feature order: k = i*16 + 2*g + t   (t=0 cos, t=1 sin)

typedef __attribute__((ext_vector_type(8))) short s16x8;
typedef __attribute__((ext_vector_type(4))) float f32x4;

#define NROWS 8192
#define IDIM  512
#define ODIM  512
#define KDIM  8192   // IDIM*16

static __device__ __forceinline__ short f2bf(float f) {
    union { float f; unsigned u; } v; v.f = f;
    unsigned r = v.u + 0x7fffu + ((v.u >> 16) & 1u);  // RNE
    return (short)(r >> 16);
}

// ---- prep: coeffs [2][O][I][G] f32  ->  Wb[O][K] bf16, k = i*16 + 2g + t ----
__global__ __launch_bounds__(256) void fkan_prep(const float* __restrict__ cf,
                                                 short* __restrict__ Wb) {
    const int o = blockIdx.x;
    const int tid = threadIdx.x;
#pragma unroll
    for (int rep = 0; rep < 2; ++rep) {
        const int i = tid + rep * 256;
        const float* c0 = cf + (o * 512 + i) * 8;            // t=0
        const float* c1 = cf + ((512 + o) * 512 + i) * 8;    // t=1
        float4 a0 = *(const float4*)c0;
        float4 a1 = *(const float4*)(c0 + 4);
        float4 b0 = *(const float4*)c1;
        float4 b1 = *(const float4*)(c1 + 4);
        s16x8 lo, hi;
        lo[0] = f2bf(a0.x); lo[1] = f2bf(b0.x);
        lo[2] = f2bf(a0.y); lo[3] = f2bf(b0.y);
        lo[4] = f2bf(a0.z); lo[5] = f2bf(b0.z);
        lo[6] = f2bf(a0.w); lo[7] = f2bf(b0.w);
        hi[0] = f2bf(a1.x); hi[1] = f2bf(b1.x);
        hi[2] = f2bf(a1.y); hi[3] = f2bf(b1.y);
        hi[4] = f2bf(a1.z); hi[5] = f2bf(b1.z);
        hi[6] = f2bf(a1.w); hi[7] = f2bf(b1.w);
        *(s16x8*)(Wb + o * KDIM + i * 16)     = lo;
        *(s16x8*)(Wb + o * KDIM + i * 16 + 8) = hi;
    }
}

// ---- fused GEMM: BM=128, BN=128, BK=64, 256 threads (4 waves, 2x2) ----
__global__ __launch_bounds__(256) void fkan_gemm(const float* __restrict__ x,
                                                 const short* __restrict__ Wb,
                                                 const float* __restrict__ bias,
                                                 float* __restrict__ out) {
    __shared__ short As[128 * 64];   // [row n_local][64 k]  XOR-swizzled chunks
    __shared__ short Bs[128 * 64];   // [row o_local][64 k]  XOR-swizzled content

    const int bid = blockIdx.x;
    // XCD-aware mapping: XCD = bid&7 gets one fixed B-panel (2MB, L2-resident)
    const int xcd = bid & 7, idx = bid >> 3;
    const int bn = xcd & 3;
    const int bm = idx + (xcd >> 2) * 32;
    const int n0 = bm * 128, o0 = bn * 128;

    const int tid = threadIdx.x;
    const int wid = tid >> 6, lane = tid & 63;
    const int lrow = lane & 15, lk = lane >> 4;
    const int wr = wid >> 1, wc = wid & 1;

    f32x4 acc[4][4];
#pragma unroll
    for (int a = 0; a < 4; ++a)
#pragma unroll
        for (int b = 0; b < 4; ++b) {
            f32x4 z = {0.f, 0.f, 0.f, 0.f};
            acc[a][b] = z;
        }

    // A staging assignment: thread -> row nl, two x values (i = kt*4 + isel*2 + ii)
    const int nl = tid >> 1, isel = tid & 1;
    const float* xrow = x + (n0 + nl) * 512 + isel * 2;

    float2 xv = *(const float2*)xrow;  // kt = 0

    for (int kt = 0; kt < 128; ++kt) {
        // ---- stage A: compute 2 x-values -> 32 bf16 features, swizzled ds_write
#pragma unroll
        for (int ii = 0; ii < 2; ++ii) {
            const float xx = ii ? xv.y : xv.x;
            const float c1 = __cosf(xx), s1 = __sinf(xx);
            float c = c1, s = s1;
            s16x8 lo, hi;
#pragma unroll
            for (int g = 0; g < 8; ++g) {
                const short cb = f2bf(c), sb = f2bf(s);
                if (g < 4) { lo[2 * g] = cb; lo[2 * g + 1] = sb; }
                else       { hi[2 * (g - 4)] = cb; hi[2 * (g - 4) + 1] = sb; }
                const float cn = c * c1 - s * s1;       // angle-addition recurrence
                s = s * c1 + c * s1;
                c = cn;
            }
            const int il = isel * 2 + ii;
            const int r = nl;
            const int cb0 = il * 2;  // logical 16B-chunk index (0..7)
            *(s16x8*)&As[r * 64 + ((cb0 ^ (r & 7))) * 8]       = lo;
            *(s16x8*)&As[r * 64 + (((cb0 + 1) ^ (r & 7))) * 8] = hi;
        }
        // ---- stage B: global_load_lds, source pre-swizzled so LDS holds
        //      chunk (r, pc) = global chunk (r, pc ^ (r&7))
#pragma unroll
        for (int w = 0; w < 4; ++w) {
            const int chunk = w * 256 + tid;      // 16B chunk within tile
            const int r = chunk >> 3, pc = chunk & 7;
            const int lc = pc ^ (r & 7);
            const short* src = Wb + (o0 + r) * KDIM + kt * 64 + lc * 8;
            short* ldst = (&Bs[0]) + w * 2048 + wid * 512;   // wave-uniform base
            __builtin_amdgcn_global_load_lds(
                (const __attribute__((address_space(1))) void*)src,
                (__attribute__((address_space(3))) void*)ldst, 16, 0, 0);
        }
        // prefetch next x one iteration ahead (covers load latency at 1 wave/SIMD)
        if (kt < 127) xv = *(const float2*)(xrow + (kt + 1) * 4);

        __syncthreads();

#pragma unroll
        for (int ksub = 0; ksub < 2; ++ksub) {
            s16x8 af[4], bfr[4];
#pragma unroll
            for (int mf = 0; mf < 4; ++mf) {
                const int row = wr * 64 + mf * 16 + lrow;
                af[mf] = *(const s16x8*)&As[row * 64 + ((ksub * 4 + lk) ^ (row & 7)) * 8];
            }
#pragma unroll
            for (int nf = 0; nf < 4; ++nf) {
                const int row = wc * 64 + nf * 16 + lrow;
                bfr[nf] = *(const s16x8*)&Bs[row * 64 + ((ksub * 4 + lk) ^ (row & 7)) * 8];
            }
#pragma unroll
            for (int mf = 0; mf < 4; ++mf)
#pragma unroll
                for (int nf = 0; nf < 4; ++nf)
                    acc[mf][nf] = __builtin_amdgcn_mfma_f32_16x16x32_bf16(
                        af[mf], bfr[nf], acc[mf][nf], 0, 0, 0);
        }
        __syncthreads();
    }

    // ---- epilogue: D layout col = lane&15 (o), row = (lane>>4)*4 + reg (n)
#pragma unroll
    for (int nf = 0; nf < 4; ++nf) {
        const int oc = o0 + wc * 64 + nf * 16 + lrow;
        const float bv = bias[oc];
#pragma unroll
        for (int mf = 0; mf < 4; ++mf) {
            const f32x4 v = acc[mf][nf];
            const int rbase = n0 + wr * 64 + mf * 16 + lk * 4;
#pragma unroll
            for (int j = 0; j < 4; ++j)
                out[(rbase + j) * 512 + oc] = v[j] + bv;
        }
    }
}

extern "C" void kernel_launch(void* const* d_in, const int* in_sizes, int n_in,
                              void* d_out, int out_size, void* d_ws, size_t ws_size,
                              hipStream_t stream) {
    const float* x    = (const float*)d_in[0];
    const float* cf   = (const float*)d_in[1];
    const float* bias = (const float*)d_in[2];
    float* out = (float*)d_out;
    short* Wb = (short*)d_ws;   // 512*8192*2 = 8 MB

    fkan_prep<<<512, 256, 0, stream>>>(cf, Wb);
    fkan_gemm<<<256, 256, 0, stream>>>(x, Wb, bias, out);
}

// Round 2
// 119.807 us; speedup vs baseline: 1.3594x; 1.3594x over previous
//
#include <hip/hip_runtime.h>

// FourierKANLayer: y[n,o] = sum_{i,g} cos(x[n,i]*(g+1))*C[0,o,i,g]
//                         + sin(x[n,i]*(g+1))*C[1,o,i,g] + bias[o]
// N=8192 rows, I=512, O=512, G=8  ->  GEMM  [N x K] * [K x O], K = I*16 = 8192
// Feature order: k = i*16 + 2*g + t   (t=0 cos, t=1 sin)
// Round 2: K-split=2 -> 512 blocks = 2 blocks/CU so trig-VALU/staging of one
// block overlaps MFMA of the other (independent barrier domains).

typedef __attribute__((ext_vector_type(8))) short s16x8;
typedef __attribute__((ext_vector_type(4))) float f32x4;

#define NROWS 8192
#define IDIM  512
#define ODIM  512
#define KDIM  8192   // IDIM*16

static __device__ __forceinline__ short f2bf(float f) {
    union { float f; unsigned u; } v; v.f = f;
    unsigned r = v.u + 0x7fffu + ((v.u >> 16) & 1u);  // RNE
    return (short)(r >> 16);
}

// ---- prep: coeffs [2][O][I][G] f32  ->  Wb[O][K] bf16, k = i*16 + 2g + t ----
__global__ __launch_bounds__(256) void fkan_prep(const float* __restrict__ cf,
                                                 short* __restrict__ Wb) {
    const int o = blockIdx.x;
    const int tid = threadIdx.x;
#pragma unroll
    for (int rep = 0; rep < 2; ++rep) {
        const int i = tid + rep * 256;
        const float* c0 = cf + (o * 512 + i) * 8;            // t=0
        const float* c1 = cf + ((512 + o) * 512 + i) * 8;    // t=1
        float4 a0 = *(const float4*)c0;
        float4 a1 = *(const float4*)(c0 + 4);
        float4 b0 = *(const float4*)c1;
        float4 b1 = *(const float4*)(c1 + 4);
        s16x8 lo, hi;
        lo[0] = f2bf(a0.x); lo[1] = f2bf(b0.x);
        lo[2] = f2bf(a0.y); lo[3] = f2bf(b0.y);
        lo[4] = f2bf(a0.z); lo[5] = f2bf(b0.z);
        lo[6] = f2bf(a0.w); lo[7] = f2bf(b0.w);
        hi[0] = f2bf(a1.x); hi[1] = f2bf(b1.x);
        hi[2] = f2bf(a1.y); hi[3] = f2bf(b1.y);
        hi[4] = f2bf(a1.z); hi[5] = f2bf(b1.z);
        hi[6] = f2bf(a1.w); hi[7] = f2bf(b1.w);
        *(s16x8*)(Wb + o * KDIM + i * 16)     = lo;
        *(s16x8*)(Wb + o * KDIM + i * 16 + 8) = hi;
    }
}

// ---- fused GEMM: BM=128, BN=128, BK=64, 256 threads (4 waves, 2x2) ----
// KSPLIT=2: grid 512, each block does half of K, writes f32 partial (no bias).
// KSPLIT=1: grid 256, full K, writes out + bias (fallback when ws too small).
template <int KSPLIT>
__global__ __launch_bounds__(256) void fkan_gemm(const float* __restrict__ x,
                                                 const short* __restrict__ Wb,
                                                 const float* __restrict__ bias,
                                                 float* __restrict__ outp) {
    __shared__ short As[128 * 64];   // [row n_local][64 k]  XOR-swizzled chunks
    __shared__ short Bs[128 * 64];   // [row o_local][64 k]  XOR-swizzled content

    const int bid = blockIdx.x;
    int bn, kc, bm;
    if (KSPLIT == 2) {
        // 8 (bn,kc) combos -> 8 XCDs; each XCD's 1MB B-chunk is L2-resident.
        const int xcd = bid & 7;
        bn = xcd & 3; kc = xcd >> 2; bm = bid >> 3;          // bm in [0,64)
    } else {
        const int xcd = bid & 7, idx = bid >> 3;
        bn = xcd & 3; kc = 0; bm = idx + (xcd >> 2) * 32;    // bm in [0,64)
    }
    const int n0 = bm * 128, o0 = bn * 128;
    const int NKT = 128 / KSPLIT;          // kt iterations
    const int i0 = kc * (512 / KSPLIT);    // starting input-dim index
    const int kbase = i0 * 16;             // starting k index in Wb

    const int tid = threadIdx.x;
    const int wid = tid >> 6, lane = tid & 63;
    const int lrow = lane & 15, lk = lane >> 4;
    const int wr = wid >> 1, wc = wid & 1;

    f32x4 acc[4][4];
#pragma unroll
    for (int a = 0; a < 4; ++a)
#pragma unroll
        for (int b = 0; b < 4; ++b) {
            f32x4 z = {0.f, 0.f, 0.f, 0.f};
            acc[a][b] = z;
        }

    // A staging assignment: thread -> row nl, two x values (i = i0 + kt*4 + isel*2 + ii)
    const int nl = tid >> 1, isel = tid & 1;
    const float* xrow = x + (n0 + nl) * 512 + i0 + isel * 2;

    float2 xv = *(const float2*)xrow;  // kt = 0

    for (int kt = 0; kt < NKT; ++kt) {
        // ---- stage A: compute 2 x-values -> 32 bf16 features, swizzled ds_write
#pragma unroll
        for (int ii = 0; ii < 2; ++ii) {
            const float xx = ii ? xv.y : xv.x;
            const float c1 = __cosf(xx), s1 = __sinf(xx);
            float c = c1, s = s1;
            s16x8 lo, hi;
#pragma unroll
            for (int g = 0; g < 8; ++g) {
                const short cb = f2bf(c), sb = f2bf(s);
                if (g < 4) { lo[2 * g] = cb; lo[2 * g + 1] = sb; }
                else       { hi[2 * (g - 4)] = cb; hi[2 * (g - 4) + 1] = sb; }
                const float cn = c * c1 - s * s1;       // angle-addition recurrence
                s = s * c1 + c * s1;
                c = cn;
            }
            const int il = isel * 2 + ii;
            const int r = nl;
            const int cb0 = il * 2;  // logical 16B-chunk index (0..7)
            *(s16x8*)&As[r * 64 + ((cb0 ^ (r & 7))) * 8]       = lo;
            *(s16x8*)&As[r * 64 + (((cb0 + 1) ^ (r & 7))) * 8] = hi;
        }
        // ---- stage B: global_load_lds, source pre-swizzled so LDS holds
        //      chunk (r, pc) = global chunk (r, pc ^ (r&7))
#pragma unroll
        for (int w = 0; w < 4; ++w) {
            const int chunk = w * 256 + tid;      // 16B chunk within tile
            const int r = chunk >> 3, pc = chunk & 7;
            const int lc = pc ^ (r & 7);
            const short* src = Wb + (o0 + r) * KDIM + kbase + kt * 64 + lc * 8;
            short* ldst = (&Bs[0]) + w * 2048 + wid * 512;   // wave-uniform base
            __builtin_amdgcn_global_load_lds(
                (const __attribute__((address_space(1))) void*)src,
                (__attribute__((address_space(3))) void*)ldst, 16, 0, 0);
        }
        // prefetch next x one iteration ahead
        if (kt < NKT - 1) xv = *(const float2*)(xrow + (kt + 1) * 4);

        __syncthreads();

#pragma unroll
        for (int ksub = 0; ksub < 2; ++ksub) {
            s16x8 af[4], bfr[4];
#pragma unroll
            for (int mf = 0; mf < 4; ++mf) {
                const int row = wr * 64 + mf * 16 + lrow;
                af[mf] = *(const s16x8*)&As[row * 64 + ((ksub * 4 + lk) ^ (row & 7)) * 8];
            }
#pragma unroll
            for (int nf = 0; nf < 4; ++nf) {
                const int row = wc * 64 + nf * 16 + lrow;
                bfr[nf] = *(const s16x8*)&Bs[row * 64 + ((ksub * 4 + lk) ^ (row & 7)) * 8];
            }
#pragma unroll
            for (int mf = 0; mf < 4; ++mf)
#pragma unroll
                for (int nf = 0; nf < 4; ++nf)
                    acc[mf][nf] = __builtin_amdgcn_mfma_f32_16x16x32_bf16(
                        af[mf], bfr[nf], acc[mf][nf], 0, 0, 0);
        }
        __syncthreads();
    }

    // ---- epilogue: D layout col = lane&15 (o), row = (lane>>4)*4 + reg (n)
    float* dst = (KSPLIT == 2) ? (outp + (size_t)kc * (NROWS * ODIM)) : outp;
#pragma unroll
    for (int nf = 0; nf < 4; ++nf) {
        const int oc = o0 + wc * 64 + nf * 16 + lrow;
        const float bv = (KSPLIT == 1) ? bias[oc] : 0.f;
#pragma unroll
        for (int mf = 0; mf < 4; ++mf) {
            const f32x4 v = acc[mf][nf];
            const int rbase = n0 + wr * 64 + mf * 16 + lk * 4;
#pragma unroll
            for (int j = 0; j < 4; ++j)
                dst[(rbase + j) * 512 + oc] = v[j] + bv;
        }
    }
}

// ---- combine: out = P0 + P1 + bias ----
__global__ __launch_bounds__(256) void fkan_combine(const float* __restrict__ P,
                                                    const float* __restrict__ bias,
                                                    float* __restrict__ out) {
    const int total = NROWS * ODIM / 4;  // float4 count
    for (int idx = blockIdx.x * 256 + threadIdx.x; idx < total;
         idx += gridDim.x * 256) {
        float4 a = ((const float4*)P)[idx];
        float4 b = ((const float4*)P)[total + idx];
        float4 c = ((const float4*)bias)[idx & 127];
        float4 r;
        r.x = a.x + b.x + c.x;
        r.y = a.y + b.y + c.y;
        r.z = a.z + b.z + c.z;
        r.w = a.w + b.w + c.w;
        ((float4*)out)[idx] = r;
    }
}

extern "C" void kernel_launch(void* const* d_in, const int* in_sizes, int n_in,
                              void* d_out, int out_size, void* d_ws, size_t ws_size,
                              hipStream_t stream) {
    const float* x    = (const float*)d_in[0];
    const float* cf   = (const float*)d_in[1];
    const float* bias = (const float*)d_in[2];
    float* out = (float*)d_out;

    const size_t partial_bytes = (size_t)2 * NROWS * ODIM * 4;   // 33.6 MB
    const size_t wb_bytes = (size_t)ODIM * KDIM * 2;             // 8.4 MB

    if (ws_size >= partial_bytes + wb_bytes) {
        float* P  = (float*)d_ws;
        short* Wb = (short*)((char*)d_ws + partial_bytes);
        fkan_prep<<<512, 256, 0, stream>>>(cf, Wb);
        fkan_gemm<2><<<512, 256, 0, stream>>>(x, Wb, bias, P);
        fkan_combine<<<1024, 256, 0, stream>>>(P, bias, out);
    } else {
        short* Wb = (short*)d_ws;
        fkan_prep<<<512, 256, 0, stream>>>(cf, Wb);
        fkan_gemm<1><<<256, 256, 0, stream>>>(x, Wb, bias, out);
    }
}

// Round 3
// 100.691 us; speedup vs baseline: 1.6175x; 1.1899x over previous
//
#include <hip/hip_runtime.h>
#include <hip/hip_bf16.h>

// FourierKANLayer: y[n,o] = sum_{i,g} cos(x[n,i]*(g+1))*C[0,o,i,g]
//                         + sin(x[n,i]*(g+1))*C[1,o,i,g] + bias[o]
// N=8192 rows, I=512, O=512, G=8  ->  GEMM  [N x K] * [K x O], K = I*16 = 8192
// Feature order: k = i*16 + 2*g + t   (t=0 cos, t=1 sin)
// Round 3: (a) v_cvt_pk_bf16_f32 packing (b) double-buffered LDS, single
// barrier per K-step so trig-VALU(kt+1) interleaves with MFMA(kt).

typedef __attribute__((ext_vector_type(8))) short s16x8;
typedef __attribute__((ext_vector_type(4))) int   i32x4;
typedef __attribute__((ext_vector_type(4))) float f32x4;

#define NROWS 8192
#define IDIM  512
#define ODIM  512
#define KDIM  8192   // IDIM*16

static __device__ __forceinline__ short f2bf(float f) {
    union { float f; unsigned u; } v; v.f = f;
    unsigned r = v.u + 0x7fffu + ((v.u >> 16) & 1u);  // RNE
    return (short)(r >> 16);
}

static __device__ __forceinline__ int pkbf(float c, float s) {
    union { __hip_bfloat162 h; int i; } u;
    u.h = __float22bfloat162_rn(make_float2(c, s));   // low = cos, high = sin
    return u.i;
}

// ---- prep: coeffs [2][O][I][G] f32  ->  Wb[O][K] bf16, k = i*16 + 2g + t ----
__global__ __launch_bounds__(256) void fkan_prep(const float* __restrict__ cf,
                                                 short* __restrict__ Wb) {
    const int o = blockIdx.x;
    const int tid = threadIdx.x;
#pragma unroll
    for (int rep = 0; rep < 2; ++rep) {
        const int i = tid + rep * 256;
        const float* c0 = cf + (o * 512 + i) * 8;            // t=0
        const float* c1 = cf + ((512 + o) * 512 + i) * 8;    // t=1
        float4 a0 = *(const float4*)c0;
        float4 a1 = *(const float4*)(c0 + 4);
        float4 b0 = *(const float4*)c1;
        float4 b1 = *(const float4*)(c1 + 4);
        s16x8 lo, hi;
        lo[0] = f2bf(a0.x); lo[1] = f2bf(b0.x);
        lo[2] = f2bf(a0.y); lo[3] = f2bf(b0.y);
        lo[4] = f2bf(a0.z); lo[5] = f2bf(b0.z);
        lo[6] = f2bf(a0.w); lo[7] = f2bf(b0.w);
        hi[0] = f2bf(a1.x); hi[1] = f2bf(b1.x);
        hi[2] = f2bf(a1.y); hi[3] = f2bf(b1.y);
        hi[4] = f2bf(a1.z); hi[5] = f2bf(b1.z);
        hi[6] = f2bf(a1.w); hi[7] = f2bf(b1.w);
        *(s16x8*)(Wb + o * KDIM + i * 16)     = lo;
        *(s16x8*)(Wb + o * KDIM + i * 16 + 8) = hi;
    }
}

// ---- fused GEMM: BM=128, BN=128, BK=64, 256 threads (4 waves, 2x2) ----
// KSPLIT=2: grid 512, each block does half of K, writes f32 partial (no bias).
// KSPLIT=1: grid 256, full K, writes out + bias (fallback when ws too small).
template <int KSPLIT>
__global__ __launch_bounds__(256, 2) void fkan_gemm(const float* __restrict__ x,
                                                    const short* __restrict__ Wb,
                                                    const float* __restrict__ bias,
                                                    float* __restrict__ outp) {
    __shared__ short As[2][128 * 64];   // [buf][row n_local][64 k] swizzled chunks
    __shared__ short Bs[2][128 * 64];   // [buf][row o_local][64 k] swizzled content

    const int bid = blockIdx.x;
    int bn, kc, bm;
    if (KSPLIT == 2) {
        // 8 (bn,kc) combos -> 8 XCDs; each XCD's 1MB B-chunk is L2-resident.
        const int xcd = bid & 7;
        bn = xcd & 3; kc = xcd >> 2; bm = bid >> 3;          // bm in [0,64)
    } else {
        const int xcd = bid & 7, idx = bid >> 3;
        bn = xcd & 3; kc = 0; bm = idx + (xcd >> 2) * 32;    // bm in [0,64)
    }
    const int n0 = bm * 128, o0 = bn * 128;
    const int NKT = 128 / KSPLIT;          // kt iterations
    const int i0 = kc * (512 / KSPLIT);    // starting input-dim index
    const int kbase = i0 * 16;             // starting k index in Wb

    const int tid = threadIdx.x;
    const int wid = tid >> 6, lane = tid & 63;
    const int lrow = lane & 15, lk = lane >> 4;
    const int wr = wid >> 1, wc = wid & 1;

    f32x4 acc[4][4];
#pragma unroll
    for (int a = 0; a < 4; ++a)
#pragma unroll
        for (int b = 0; b < 4; ++b) {
            f32x4 z = {0.f, 0.f, 0.f, 0.f};
            acc[a][b] = z;
        }

    // A staging assignment: thread -> row nl, two x values (i = i0 + kt*4 + isel*2 + ii)
    const int nl = tid >> 1, isel = tid & 1;
    const float* xrow = x + (n0 + nl) * 512 + i0 + isel * 2;

    // stage tile t into buffer nb (trig A + gload_lds B)
    auto stage = [&](int t, int nb, float2 xvv) {
#pragma unroll
        for (int w = 0; w < 4; ++w) {
            const int chunk = w * 256 + tid;      // 16B chunk within tile
            const int r = chunk >> 3, pc = chunk & 7;
            const int lc = pc ^ (r & 7);
            const short* src = Wb + (o0 + r) * KDIM + kbase + t * 64 + lc * 8;
            short* ldst = &Bs[nb][w * 2048 + wid * 512];   // wave-uniform base
            __builtin_amdgcn_global_load_lds(
                (const __attribute__((address_space(1))) void*)src,
                (__attribute__((address_space(3))) void*)ldst, 16, 0, 0);
        }
#pragma unroll
        for (int ii = 0; ii < 2; ++ii) {
            const float xx = ii ? xvv.y : xvv.x;
            float s1, c1;
            __sincosf(xx, &s1, &c1);
            float c = c1, s = s1;
            i32x4 lo, hi;
#pragma unroll
            for (int g = 0; g < 8; ++g) {
                const int p = pkbf(c, s);
                if (g < 4) lo[g] = p; else hi[g - 4] = p;
                const float t1 = s * s1, t2 = c * s1;
                const float cn = __builtin_fmaf(c, c1, -t1);  // cos(k+1)
                s = __builtin_fmaf(s, c1, t2);                // sin(k+1)
                c = cn;
            }
            const int il = isel * 2 + ii;
            const int cb0 = il * 2;  // logical 16B-chunk index (0..7)
            *(i32x4*)&As[nb][nl * 64 + ((cb0 ^ (nl & 7))) * 8]       = lo;
            *(i32x4*)&As[nb][nl * 64 + (((cb0 + 1) ^ (nl & 7))) * 8] = hi;
        }
    };

    float2 xv = *(const float2*)xrow;          // x for tile 0
    stage(0, 0, xv);
    xv = *(const float2*)(xrow + 4);           // x for tile 1
    __syncthreads();

    for (int kt = 0; kt < NKT; ++kt) {
        const int cur = kt & 1;
        const short* Ab = As[cur];
        const short* Bb = Bs[cur];

        // ---- read all fragments for this tile (addresses loop-invariant)
        s16x8 af[2][4], bfr[2][4];
#pragma unroll
        for (int ksub = 0; ksub < 2; ++ksub) {
#pragma unroll
            for (int mf = 0; mf < 4; ++mf) {
                const int row = wr * 64 + mf * 16 + lrow;
                af[ksub][mf] = *(const s16x8*)&Ab[row * 64 + ((ksub * 4 + lk) ^ (row & 7)) * 8];
            }
#pragma unroll
            for (int nf = 0; nf < 4; ++nf) {
                const int row = wc * 64 + nf * 16 + lrow;
                bfr[ksub][nf] = *(const s16x8*)&Bb[row * 64 + ((ksub * 4 + lk) ^ (row & 7)) * 8];
            }
        }

        // ---- stage next tile into the other buffer (overlaps with MFMA below)
        if (kt + 1 < NKT) {
            stage(kt + 1, cur ^ 1, xv);
            if (kt + 2 < NKT) xv = *(const float2*)(xrow + (kt + 2) * 4);
        }

        // ---- MFMA
#pragma unroll
        for (int ksub = 0; ksub < 2; ++ksub)
#pragma unroll
            for (int mf = 0; mf < 4; ++mf)
#pragma unroll
                for (int nf = 0; nf < 4; ++nf)
                    acc[mf][nf] = __builtin_amdgcn_mfma_f32_16x16x32_bf16(
                        af[ksub][mf], bfr[ksub][nf], acc[mf][nf], 0, 0, 0);

        __syncthreads();   // drains vmcnt+lgkm; protects both buffers
    }

    // ---- epilogue: D layout col = lane&15 (o), row = (lane>>4)*4 + reg (n)
    float* dst = (KSPLIT == 2) ? (outp + (size_t)kc * (NROWS * ODIM)) : outp;
#pragma unroll
    for (int nf = 0; nf < 4; ++nf) {
        const int oc = o0 + wc * 64 + nf * 16 + lrow;
        const float bv = (KSPLIT == 1) ? bias[oc] : 0.f;
#pragma unroll
        for (int mf = 0; mf < 4; ++mf) {
            const f32x4 v = acc[mf][nf];
            const int rbase = n0 + wr * 64 + mf * 16 + lk * 4;
#pragma unroll
            for (int j = 0; j < 4; ++j)
                dst[(rbase + j) * 512 + oc] = v[j] + bv;
        }
    }
}

// ---- combine: out = P0 + P1 + bias ----
__global__ __launch_bounds__(256) void fkan_combine(const float* __restrict__ P,
                                                    const float* __restrict__ bias,
                                                    float* __restrict__ out) {
    const int total = NROWS * ODIM / 4;  // float4 count
    for (int idx = blockIdx.x * 256 + threadIdx.x; idx < total;
         idx += gridDim.x * 256) {
        float4 a = ((const float4*)P)[idx];
        float4 b = ((const float4*)P)[total + idx];
        float4 c = ((const float4*)bias)[idx & 127];
        float4 r;
        r.x = a.x + b.x + c.x;
        r.y = a.y + b.y + c.y;
        r.z = a.z + b.z + c.z;
        r.w = a.w + b.w + c.w;
        ((float4*)out)[idx] = r;
    }
}

extern "C" void kernel_launch(void* const* d_in, const int* in_sizes, int n_in,
                              void* d_out, int out_size, void* d_ws, size_t ws_size,
                              hipStream_t stream) {
    const float* x    = (const float*)d_in[0];
    const float* cf   = (const float*)d_in[1];
    const float* bias = (const float*)d_in[2];
    float* out = (float*)d_out;

    const size_t partial_bytes = (size_t)2 * NROWS * ODIM * 4;   // 33.6 MB
    const size_t wb_bytes = (size_t)ODIM * KDIM * 2;             // 8.4 MB

    if (ws_size >= partial_bytes + wb_bytes) {
        float* P  = (float*)d_ws;
        short* Wb = (short*)((char*)d_ws + partial_bytes);
        fkan_prep<<<512, 256, 0, stream>>>(cf, Wb);
        fkan_gemm<2><<<512, 256, 0, stream>>>(x, Wb, bias, P);
        fkan_combine<<<1024, 256, 0, stream>>>(P, bias, out);
    } else {
        short* Wb = (short*)d_ws;
        fkan_prep<<<512, 256, 0, stream>>>(cf, Wb);
        fkan_gemm<1><<<256, 256, 0, stream>>>(x, Wb, bias, out);
    }
}